// Round 15
// baseline (290.606 us; speedup 1.0000x reference)
//
#include <hip/hip_runtime.h>

typedef float  f32x4  __attribute__((ext_vector_type(4)));
typedef float  f32x16 __attribute__((ext_vector_type(16)));
typedef short  short8 __attribute__((ext_vector_type(8)));
typedef unsigned int uint4v __attribute__((ext_vector_type(4)));

#define LOG2E 1.4426950408889634f
#define NPIX 4096
#define CCH  512
#define DQK  64

__device__ __forceinline__ ushort f2b(float f) {
  union { float f; unsigned u; } v; v.f = f;
  unsigned r = v.u + 0x7fffu + ((v.u >> 16) & 1u);
  return (ushort)(r >> 16);
}

__device__ __forceinline__ unsigned cvt_pk_bf16(float lo, float hi) {
  unsigned r;
  asm("v_cvt_pk_bf16_f32 %0, %1, %2" : "=v"(r) : "v"(lo), "v"(hi));
  return r;
}

// in-place half-swap: a' = {a[0:32), b[0:32)}, b' = {a[32:64), b[32:64)}
__device__ __forceinline__ void plane_swap(unsigned &a, unsigned &b) {
  asm volatile("v_permlane32_swap_b32 %0, %1" : "+v"(a), "+v"(b));
}

// x: [B][C][N] f32  ->  Xt: [B][N][C] bf16  (tiled transpose via LDS)
__global__ __launch_bounds__(256) void k_cast_x(const float* __restrict__ x,
                                                ushort* __restrict__ Xt) {
  __shared__ float tile[32][33];
  const int b = blockIdx.z;
  const int n0 = blockIdx.x * 32, c0 = blockIdx.y * 32;
  const int t = threadIdx.x;
  {
    int cc = t >> 3, nn = (t & 7) * 4;
    const float4 v = *(const float4*)&x[((size_t)b * CCH + c0 + cc) * NPIX + n0 + nn];
    tile[cc][nn] = v.x; tile[cc][nn + 1] = v.y; tile[cc][nn + 2] = v.z; tile[cc][nn + 3] = v.w;
  }
  __syncthreads();
  {
    int nr = t >> 3, c4 = (t & 7) * 4;
    ushort4 o;
    o.x = f2b(tile[c4 + 0][nr]); o.y = f2b(tile[c4 + 1][nr]);
    o.z = f2b(tile[c4 + 2][nr]); o.w = f2b(tile[c4 + 3][nr]);
    *(ushort4*)&Xt[((size_t)b * NPIX + n0 + nr) * CCH + c0 + c4] = o;
  }
}

// pack wq(64x512), wk(64x512), wv(512x512) -> Wb[640][512] bf16
__global__ __launch_bounds__(256) void k_cast_w(const float* __restrict__ wq,
                                                const float* __restrict__ wk,
                                                const float* __restrict__ wv,
                                                ushort* __restrict__ Wb) {
  int i = blockIdx.x * 256 + threadIdx.x;
  int idx = i * 4;
  int j = idx >> 9, c = idx & 511;
  const float* src = (j < 64) ? &wq[(size_t)j * 512]
                   : (j < 128) ? &wk[(size_t)(j - 64) * 512]
                               : &wv[(size_t)(j - 128) * 512];
  float4 v = *(const float4*)&src[c];
  ushort4 o; o.x = f2b(v.x); o.y = f2b(v.y); o.z = f2b(v.z); o.w = f2b(v.w);
  *(ushort4*)&Wb[idx] = o;
}

// QKV projection GEMM: out[j,n] = sum_c Wb[j,c]*Xt[n,c] + bias[j]
// Q: [B][N][64] row-major (pre-scaled by LOG2E).
// K: fragment-order Kf[b][n32][ks:4][lane:64][e:8]
// V: fragment-order Vf[b][n32][c32:16][kt:2][lane:64][e:8]
__global__ __launch_bounds__(256) void k_proj(const ushort* __restrict__ Xt,
                                              const ushort* __restrict__ Wb,
                                              const float* __restrict__ bq,
                                              const float* __restrict__ bk,
                                              const float* __restrict__ bv,
                                              ushort* __restrict__ Q,
                                              ushort* __restrict__ Kf,
                                              ushort* __restrict__ Vf) {
  __shared__ ushort Wl[64][72];
  __shared__ ushort Xl[64][72];
  const int b = blockIdx.z;
  const int n0 = blockIdx.x * 64;
  const int j0 = blockIdx.y * 64;
  const int t = threadIdx.x;
  const int w = t >> 6, l = t & 63;
  const int lr = l & 15, lq = l >> 4;
  const int wj = (w >> 1) * 32, wn = (w & 1) * 32;

  f32x4 acc[2][2];
#pragma unroll
  for (int a = 0; a < 2; ++a)
#pragma unroll
    for (int c = 0; c < 2; ++c) acc[a][c] = f32x4{0.f, 0.f, 0.f, 0.f};

  const int srow = t >> 2, sch = t & 3;
  for (int k0 = 0; k0 < 512; k0 += 64) {
    *(uint4*)&Wl[srow][sch * 8]       = *(const uint4*)&Wb[(size_t)(j0 + srow) * 512 + k0 + sch * 8];
    *(uint4*)&Wl[srow][(sch + 4) * 8] = *(const uint4*)&Wb[(size_t)(j0 + srow) * 512 + k0 + (sch + 4) * 8];
    *(uint4*)&Xl[srow][sch * 8]       = *(const uint4*)&Xt[((size_t)b * NPIX + n0 + srow) * 512 + k0 + sch * 8];
    *(uint4*)&Xl[srow][(sch + 4) * 8] = *(const uint4*)&Xt[((size_t)b * NPIX + n0 + srow) * 512 + k0 + (sch + 4) * 8];
    __syncthreads();
#pragma unroll
    for (int kt = 0; kt < 2; ++kt) {
      short8 af[2], bf[2];
#pragma unroll
      for (int jt = 0; jt < 2; ++jt)
        af[jt] = *(const short8*)&Wl[wj + jt * 16 + lr][kt * 32 + lq * 8];
#pragma unroll
      for (int nt = 0; nt < 2; ++nt)
        bf[nt] = *(const short8*)&Xl[wn + nt * 16 + lr][kt * 32 + lq * 8];
#pragma unroll
      for (int jt = 0; jt < 2; ++jt)
#pragma unroll
        for (int nt = 0; nt < 2; ++nt)
          acc[jt][nt] = __builtin_amdgcn_mfma_f32_16x16x32_bf16(af[jt], bf[nt], acc[jt][nt], 0, 0, 0);
    }
    __syncthreads();
  }

#pragma unroll
  for (int jt = 0; jt < 2; ++jt) {
    const int jb = j0 + wj + jt * 16;
#pragma unroll
    for (int nt = 0; nt < 2; ++nt) {
      const int n = n0 + wn + nt * 16 + lr;
      const size_t nrow = (size_t)b * NPIX + n;
      const int n32 = (n0 + wn) >> 5;
      if (jb < 64) {
        ushort4 o;
        o.x = f2b(LOG2E * (acc[jt][nt][0] + bq[jb + lq * 4 + 0]));
        o.y = f2b(LOG2E * (acc[jt][nt][1] + bq[jb + lq * 4 + 1]));
        o.z = f2b(LOG2E * (acc[jt][nt][2] + bq[jb + lq * 4 + 2]));
        o.w = f2b(LOG2E * (acc[jt][nt][3] + bq[jb + lq * 4 + 3]));
        *(ushort4*)&Q[nrow * DQK + jb + lq * 4] = o;
      } else if (jb < 128) {
        const int kd0 = jb - 64 + lq * 4;
        const int ks = (jb - 64) >> 4;
        const int hl = lq >> 1;
        const int e0 = (lq * 4) & 7;
        const int lp = (nt * 16 + lr) + 32 * hl;
        ushort4 o;
        o.x = f2b(acc[jt][nt][0] + bk[kd0 + 0]);
        o.y = f2b(acc[jt][nt][1] + bk[kd0 + 1]);
        o.z = f2b(acc[jt][nt][2] + bk[kd0 + 2]);
        o.w = f2b(acc[jt][nt][3] + bk[kd0 + 3]);
        *(ushort4*)&Kf[((size_t)(b * 128 + n32) * 4 + ks) * 512 + lp * 8 + e0] = o;
      } else {
        const int kt = nt;
        const int hlv = (lr >> 3) & 1;
        const int e = lr & 7;
#pragma unroll
        for (int r = 0; r < 4; ++r) {
          const int c = jb - 128 + lq * 4 + r;
          Vf[(((size_t)(b * 128 + n32) * 16 + (c >> 5)) * 2 + kt) * 512 +
             (c & 31) * 8 + 256 * hlv + e] = f2b(acc[jt][nt][r] + bv[c]);
        }
      }
    }
  }
}

// flash attention v15: v14 P-sharing + latency hoisting.
// Q hoisted out of tile loop; K(tile+1) prefetched right after the barrier
// (kf dead after QK); V(k8=0) prefetched before producer (lands under
// QK+softmax); depth-1 V pipeline in consumer. Geometry unchanged:
// 512 thr / 8 waves = 64q x 512c, grid 64qb x 8b = 512 = 2 blocks/CU.
__global__ __launch_bounds__(512, 4) void k_attn(const ushort* __restrict__ Qb,
                                                 const ushort* __restrict__ Kf,
                                                 const ushort* __restrict__ Vf,
                                                 const float* __restrict__ x,
                                                 const float* __restrict__ gamma,
                                                 float* __restrict__ out) {
  __shared__ unsigned Plds[2][8][2][2][64][2];  // [buf][k16][q32][j2][lane][pair] = 32KB
  __shared__ float Lred[2][4][32];              // [q32][kg][q] partial L sums
  const int id = blockIdx.x;
  const int b  = id & 7;                        // XCD via %8 round-robin
  const int qb = id >> 3;                       // 0..63 q-strips of 64
  const int t = threadIdx.x;
  const int w = t >> 6, l = t & 63;
  const int lq = l & 31, h = l >> 5;
  const int kg = w >> 1;                        // producer key-group 0..3
  const int q32p = w & 1;                       // producer q-subtile
  const int qw = qb * 64;

  union PB { uint4v u; short8 s8; };

  const ushort* qptr  = Qb + ((size_t)b * NPIX + qw + q32p * 32 + lq) * DQK + h * 8;
  const ushort* kbase = Kf + (size_t)b * 128 * 2048 + (size_t)l * 8;
  const ushort* vbase = Vf + (size_t)b * 128 * 16384 + (size_t)(2 * w) * 1024 + (size_t)l * 8;

  f32x16 acc[2][2] = {};                        // [q32][ct] for c = w*64 + ct*32
  float Lp = 0.f;

  // Q fragments: tile-invariant, loaded ONCE
  short8 q0 = *(const short8*)(qptr);
  short8 q1 = *(const short8*)(qptr + 16);
  short8 q2 = *(const short8*)(qptr + 32);
  short8 q3 = *(const short8*)(qptr + 48);

  // K fragments for tile 0
  short8 kf0 = *(const short8*)(kbase + (size_t)kg * 2048);
  short8 kf1 = *(const short8*)(kbase + (size_t)kg * 2048 + 512);
  short8 kf2 = *(const short8*)(kbase + (size_t)kg * 2048 + 1024);
  short8 kf3 = *(const short8*)(kbase + (size_t)kg * 2048 + 1536);

  for (int tile = 0; tile < 32; ++tile) {
    const int buf = tile & 1;

    // prefetch V pair for k8=0 of this tile — lands under producer phase
    const ushort* pvt = vbase + (size_t)(tile * 4) * 16384;
    short8 v0 = *(const short8*)(pvt);
    short8 v1 = *(const short8*)(pvt + 1024);

    // ---- producer: QK + softmax for keys [tile*128 + kg*32, +32), cols q32p
    {
      f32x16 s = {};
      __builtin_amdgcn_s_setprio(1);
      s = __builtin_amdgcn_mfma_f32_32x32x16_bf16(kf0, q0, s, 0, 0, 0);
      s = __builtin_amdgcn_mfma_f32_32x32x16_bf16(kf1, q1, s, 0, 0, 0);
      s = __builtin_amdgcn_mfma_f32_32x32x16_bf16(kf2, q2, s, 0, 0, 0);
      s = __builtin_amdgcn_mfma_f32_32x32x16_bf16(kf3, q3, s, 0, 0, 0);
      __builtin_amdgcn_s_setprio(0);

      float sum = 0.f;
#pragma unroll
      for (int r = 0; r < 16; ++r) { s[r] = __builtin_amdgcn_exp2f(s[r]); sum += s[r]; }
      Lp += sum;
      unsigned pk0 = cvt_pk_bf16(s[0],  s[1]),  pk1 = cvt_pk_bf16(s[2],  s[3]);
      unsigned pk2 = cvt_pk_bf16(s[4],  s[5]),  pk3 = cvt_pk_bf16(s[6],  s[7]);
      unsigned pk4 = cvt_pk_bf16(s[8],  s[9]),  pk5 = cvt_pk_bf16(s[10], s[11]);
      unsigned pk6 = cvt_pk_bf16(s[12], s[13]), pk7 = cvt_pk_bf16(s[14], s[15]);
      plane_swap(pk0, pk2); plane_swap(pk1, pk3);
      plane_swap(pk4, pk6); plane_swap(pk5, pk7);
      *(uint2*)&Plds[buf][kg * 2 + 0][q32p][0][l][0] = uint2{pk0, pk1};
      *(uint2*)&Plds[buf][kg * 2 + 0][q32p][1][l][0] = uint2{pk2, pk3};
      *(uint2*)&Plds[buf][kg * 2 + 1][q32p][0][l][0] = uint2{pk4, pk5};
      *(uint2*)&Plds[buf][kg * 2 + 1][q32p][1][l][0] = uint2{pk6, pk7};
    }
    __syncthreads();

    // prefetch K for next tile (kf regs dead after QK above)
    {
      const int tn = (tile + 1) & 31;
      const ushort* pkn = kbase + (size_t)(tn * 4 + kg) * 2048;
      kf0 = *(const short8*)(pkn);
      kf1 = *(const short8*)(pkn + 512);
      kf2 = *(const short8*)(pkn + 1024);
      kf3 = *(const short8*)(pkn + 1536);
    }

    // ---- consumer: PV over all 8 k16-slots, depth-1 V pipeline
#pragma unroll
    for (int k8 = 0; k8 < 8; ++k8) {
      short8 nv0, nv1;
      if (k8 < 7) {
        const ushort* pv = vbase + (size_t)(tile * 4 + ((k8 + 1) >> 1)) * 16384 +
                           (size_t)((k8 + 1) & 1) * 512;
        nv0 = *(const short8*)(pv);
        nv1 = *(const short8*)(pv + 1024);
      }
      uint2 a0 = *(const uint2*)&Plds[buf][k8][0][0][l][0];
      uint2 a1 = *(const uint2*)&Plds[buf][k8][0][1][l][0];
      uint2 b0 = *(const uint2*)&Plds[buf][k8][1][0][l][0];
      uint2 b1 = *(const uint2*)&Plds[buf][k8][1][1][l][0];
      PB B0, B1;
      B0.u[0] = a0.x; B0.u[1] = a0.y; B0.u[2] = a1.x; B0.u[3] = a1.y;
      B1.u[0] = b0.x; B1.u[1] = b0.y; B1.u[2] = b1.x; B1.u[3] = b1.y;
      __builtin_amdgcn_s_setprio(1);
      acc[0][0] = __builtin_amdgcn_mfma_f32_32x32x16_bf16(v0, B0.s8, acc[0][0], 0, 0, 0);
      acc[0][1] = __builtin_amdgcn_mfma_f32_32x32x16_bf16(v1, B0.s8, acc[0][1], 0, 0, 0);
      acc[1][0] = __builtin_amdgcn_mfma_f32_32x32x16_bf16(v0, B1.s8, acc[1][0], 0, 0, 0);
      acc[1][1] = __builtin_amdgcn_mfma_f32_32x32x16_bf16(v1, B1.s8, acc[1][1], 0, 0, 0);
      __builtin_amdgcn_s_setprio(0);
      if (k8 < 7) { v0 = nv0; v1 = nv1; }
    }
    // no trailing barrier: next tile writes the OTHER P buffer (dbuf ledger).
  }

  // ---- L reduction across the 4 key-groups, then epilogue
  Lp += __shfl_xor(Lp, 32);
  Lred[q32p][kg][lq] = Lp;                      // both halves write same value
  __syncthreads();
  float Lt0 = (Lred[0][0][lq] + Lred[0][1][lq]) + (Lred[0][2][lq] + Lred[0][3][lq]);
  float Lt1 = (Lred[1][0][lq] + Lred[1][1][lq]) + (Lred[1][2][lq] + Lred[1][3][lq]);
  const float g = gamma[0];
  const float gi0 = g / Lt0, gi1 = g / Lt1;
#pragma unroll
  for (int ct = 0; ct < 2; ++ct)
#pragma unroll
    for (int r = 0; r < 16; ++r) {
      const int c = w * 64 + ct * 32 + (r & 3) + 8 * (r >> 2) + 4 * h;
      const size_t base = ((size_t)b * CCH + c) * NPIX + qw + lq;
      out[base]      = gi0 * acc[0][ct][r] + x[base];
      out[base + 32] = gi1 * acc[1][ct][r] + x[base + 32];
    }
}

extern "C" void kernel_launch(void* const* d_in, const int* in_sizes, int n_in,
                              void* d_out, int out_size, void* d_ws, size_t ws_size,
                              hipStream_t stream) {
  const float* x     = (const float*)d_in[0];
  const float* wq    = (const float*)d_in[1];
  const float* bq    = (const float*)d_in[2];
  const float* wk    = (const float*)d_in[3];
  const float* bk    = (const float*)d_in[4];
  const float* wv    = (const float*)d_in[5];
  const float* bv    = (const float*)d_in[6];
  const float* gamma = (const float*)d_in[7];
  float* out = (float*)d_out;

  // Xt (32MB bf16) lives in d_out (64MB) — dead before k_attn writes the output.
  ushort* Xt = (ushort*)d_out;
  ushort* Wb = (ushort*)d_ws;                          // 640*512
  ushort* Qb = Wb + (size_t)640 * 512;                 // 8*4096*64 row-major
  ushort* Kf = Qb + (size_t)8 * NPIX * DQK;            // 8*128*4*512  (fragment-order)
  ushort* Vf = Kf + (size_t)8 * 128 * 4 * 512;         // 8*128*16*2*512 (fragment-order)
  // total ws: ~42.8 MB

  k_cast_x<<<dim3(NPIX / 32, CCH / 32, 8), 256, 0, stream>>>(x, Xt);
  k_cast_w<<<(640 * 512 / 4) / 256, 256, 0, stream>>>(wq, wk, wv, Wb);
  k_proj<<<dim3(NPIX / 64, 640 / 64, 8), 256, 0, stream>>>(Xt, Wb, bq, bk, bv, Qb, Kf, Vf);
  k_attn<<<dim3(512), 512, 0, stream>>>(Qb, Kf, Vf, x, gamma, out);
}

// Round 16
// 283.584 us; speedup vs baseline: 1.0248x; 1.0248x over previous
//
#include <hip/hip_runtime.h>

typedef float  f32x4  __attribute__((ext_vector_type(4)));
typedef float  f32x16 __attribute__((ext_vector_type(16)));
typedef short  short8 __attribute__((ext_vector_type(8)));
typedef unsigned int uint4v __attribute__((ext_vector_type(4)));

#define LOG2E 1.4426950408889634f
#define NPIX 4096
#define CCH  512
#define DQK  64

__device__ __forceinline__ ushort f2b(float f) {
  union { float f; unsigned u; } v; v.f = f;
  unsigned r = v.u + 0x7fffu + ((v.u >> 16) & 1u);
  return (ushort)(r >> 16);
}

__device__ __forceinline__ unsigned cvt_pk_bf16(float lo, float hi) {
  unsigned r;
  asm("v_cvt_pk_bf16_f32 %0, %1, %2" : "=v"(r) : "v"(lo), "v"(hi));
  return r;
}

// in-place half-swap: a' = {a[0:32), b[0:32)}, b' = {a[32:64), b[32:64)}
__device__ __forceinline__ void plane_swap(unsigned &a, unsigned &b) {
  asm volatile("v_permlane32_swap_b32 %0, %1" : "+v"(a), "+v"(b));
}

// x: [B][C][N] f32  ->  Xt: [B][N][C] bf16  (tiled transpose via LDS)
__global__ __launch_bounds__(256) void k_cast_x(const float* __restrict__ x,
                                                ushort* __restrict__ Xt) {
  __shared__ float tile[32][33];
  const int b = blockIdx.z;
  const int n0 = blockIdx.x * 32, c0 = blockIdx.y * 32;
  const int t = threadIdx.x;
  {
    int cc = t >> 3, nn = (t & 7) * 4;
    const float4 v = *(const float4*)&x[((size_t)b * CCH + c0 + cc) * NPIX + n0 + nn];
    tile[cc][nn] = v.x; tile[cc][nn + 1] = v.y; tile[cc][nn + 2] = v.z; tile[cc][nn + 3] = v.w;
  }
  __syncthreads();
  {
    int nr = t >> 3, c4 = (t & 7) * 4;
    ushort4 o;
    o.x = f2b(tile[c4 + 0][nr]); o.y = f2b(tile[c4 + 1][nr]);
    o.z = f2b(tile[c4 + 2][nr]); o.w = f2b(tile[c4 + 3][nr]);
    *(ushort4*)&Xt[((size_t)b * NPIX + n0 + nr) * CCH + c0 + c4] = o;
  }
}

// pack wq(64x512), wk(64x512), wv(512x512) -> Wb[640][512] bf16
__global__ __launch_bounds__(256) void k_cast_w(const float* __restrict__ wq,
                                                const float* __restrict__ wk,
                                                const float* __restrict__ wv,
                                                ushort* __restrict__ Wb) {
  int i = blockIdx.x * 256 + threadIdx.x;
  int idx = i * 4;
  int j = idx >> 9, c = idx & 511;
  const float* src = (j < 64) ? &wq[(size_t)j * 512]
                   : (j < 128) ? &wk[(size_t)(j - 64) * 512]
                               : &wv[(size_t)(j - 128) * 512];
  float4 v = *(const float4*)&src[c];
  ushort4 o; o.x = f2b(v.x); o.y = f2b(v.y); o.z = f2b(v.z); o.w = f2b(v.w);
  *(ushort4*)&Wb[idx] = o;
}

// QKV projection GEMM: out[j,n] = sum_c Wb[j,c]*Xt[n,c] + bias[j]
// One block per 64-n tile; loops all 10 j-tiles (Xt HBM read once, Wb L2-resident).
// Q: [B][N][64] row-major (pre-scaled by LOG2E).
// K: fragment-order Kf[b][n32][ks:4][lane:64][e:8]
// V: fragment-order Vf[b][n32][c32:16][kt:2][lane:64][e:8]
__global__ __launch_bounds__(256) void k_proj(const ushort* __restrict__ Xt,
                                              const ushort* __restrict__ Wb,
                                              const float* __restrict__ bq,
                                              const float* __restrict__ bk,
                                              const float* __restrict__ bv,
                                              ushort* __restrict__ Q,
                                              ushort* __restrict__ Kf,
                                              ushort* __restrict__ Vf) {
  __shared__ ushort Wl[64][72];
  __shared__ ushort Xl[64][72];
  const int b = blockIdx.z;
  const int n0 = blockIdx.x * 64;
  const int t = threadIdx.x;
  const int w = t >> 6, l = t & 63;
  const int lr = l & 15, lq = l >> 4;
  const int wj = (w >> 1) * 32, wn = (w & 1) * 32;
  const int srow = t >> 2, sch = t & 3;

  for (int j0 = 0; j0 < 640; j0 += 64) {
    f32x4 acc[2][2];
#pragma unroll
    for (int a = 0; a < 2; ++a)
#pragma unroll
      for (int c = 0; c < 2; ++c) acc[a][c] = f32x4{0.f, 0.f, 0.f, 0.f};

    for (int k0 = 0; k0 < 512; k0 += 64) {
      *(uint4*)&Wl[srow][sch * 8]       = *(const uint4*)&Wb[(size_t)(j0 + srow) * 512 + k0 + sch * 8];
      *(uint4*)&Wl[srow][(sch + 4) * 8] = *(const uint4*)&Wb[(size_t)(j0 + srow) * 512 + k0 + (sch + 4) * 8];
      *(uint4*)&Xl[srow][sch * 8]       = *(const uint4*)&Xt[((size_t)b * NPIX + n0 + srow) * 512 + k0 + sch * 8];
      *(uint4*)&Xl[srow][(sch + 4) * 8] = *(const uint4*)&Xt[((size_t)b * NPIX + n0 + srow) * 512 + k0 + (sch + 4) * 8];
      __syncthreads();
#pragma unroll
      for (int kt = 0; kt < 2; ++kt) {
        short8 af[2], bf[2];
#pragma unroll
        for (int jt = 0; jt < 2; ++jt)
          af[jt] = *(const short8*)&Wl[wj + jt * 16 + lr][kt * 32 + lq * 8];
#pragma unroll
        for (int nt = 0; nt < 2; ++nt)
          bf[nt] = *(const short8*)&Xl[wn + nt * 16 + lr][kt * 32 + lq * 8];
#pragma unroll
        for (int jt = 0; jt < 2; ++jt)
#pragma unroll
          for (int nt = 0; nt < 2; ++nt)
            acc[jt][nt] = __builtin_amdgcn_mfma_f32_16x16x32_bf16(af[jt], bf[nt], acc[jt][nt], 0, 0, 0);
      }
      __syncthreads();
    }

#pragma unroll
    for (int jt = 0; jt < 2; ++jt) {
      const int jb = j0 + wj + jt * 16;
#pragma unroll
      for (int nt = 0; nt < 2; ++nt) {
        const int n = n0 + wn + nt * 16 + lr;
        const size_t nrow = (size_t)b * NPIX + n;
        const int n32 = (n0 + wn) >> 5;
        if (jb < 64) {
          ushort4 o;
          o.x = f2b(LOG2E * (acc[jt][nt][0] + bq[jb + lq * 4 + 0]));
          o.y = f2b(LOG2E * (acc[jt][nt][1] + bq[jb + lq * 4 + 1]));
          o.z = f2b(LOG2E * (acc[jt][nt][2] + bq[jb + lq * 4 + 2]));
          o.w = f2b(LOG2E * (acc[jt][nt][3] + bq[jb + lq * 4 + 3]));
          *(ushort4*)&Q[nrow * DQK + jb + lq * 4] = o;
        } else if (jb < 128) {
          const int kd0 = jb - 64 + lq * 4;
          const int ks = (jb - 64) >> 4;
          const int hl = lq >> 1;
          const int e0 = (lq * 4) & 7;
          const int lp = (nt * 16 + lr) + 32 * hl;
          ushort4 o;
          o.x = f2b(acc[jt][nt][0] + bk[kd0 + 0]);
          o.y = f2b(acc[jt][nt][1] + bk[kd0 + 1]);
          o.z = f2b(acc[jt][nt][2] + bk[kd0 + 2]);
          o.w = f2b(acc[jt][nt][3] + bk[kd0 + 3]);
          *(ushort4*)&Kf[((size_t)(b * 128 + n32) * 4 + ks) * 512 + lp * 8 + e0] = o;
        } else {
          const int kt = nt;
          const int hlv = (lr >> 3) & 1;
          const int e = lr & 7;
#pragma unroll
          for (int r = 0; r < 4; ++r) {
            const int c = jb - 128 + lq * 4 + r;
            Vf[(((size_t)(b * 128 + n32) * 16 + (c >> 5)) * 2 + kt) * 512 +
               (c & 31) * 8 + 256 * hlv + e] = f2b(acc[jt][nt][r] + bv[c]);
          }
        }
      }
    }
  }
}

// flash attention v16: R14 P-sharing + depth-1 V pipeline in consumer (ONLY).
// Block = 512 thr / 8 waves = 64q x 512c. Per 128-key tile: wave w PRODUCES
// S-subtile (kg=w>>1, q32=w&1) -> softmax -> P B-frags to LDS (dbuf);
// 1 barrier; each wave CONSUMES all 8 k16-slots for its 64c slice, with the
// next V pair issued under the current 4-MFMA cluster (transient regs only —
// R14's exact 128-reg envelope preserved; R15's Q-hoist spill removed).
// grid = 64qb x 8b = 512 = 2 blocks/CU = 4 waves/SIMD.
__global__ __launch_bounds__(512, 4) void k_attn(const ushort* __restrict__ Qb,
                                                 const ushort* __restrict__ Kf,
                                                 const ushort* __restrict__ Vf,
                                                 const float* __restrict__ x,
                                                 const float* __restrict__ gamma,
                                                 float* __restrict__ out) {
  __shared__ unsigned Plds[2][8][2][2][64][2];  // [buf][k16][q32][j2][lane][pair] = 32KB
  __shared__ float Lred[2][4][32];              // [q32][kg][q] partial L sums
  const int id = blockIdx.x;
  const int b  = id & 7;                        // XCD via %8 round-robin
  const int qb = id >> 3;                       // 0..63 q-strips of 64
  const int t = threadIdx.x;
  const int w = t >> 6, l = t & 63;
  const int lq = l & 31, h = l >> 5;
  const int kg = w >> 1;                        // producer key-group 0..3
  const int q32p = w & 1;                       // producer q-subtile
  const int qw = qb * 64;

  union PB { uint4v u; short8 s8; };

  const ushort* qptr  = Qb + ((size_t)b * NPIX + qw + q32p * 32 + lq) * DQK + h * 8;
  const ushort* kbase = Kf + (size_t)b * 128 * 2048 + (size_t)l * 8;
  const ushort* vbase = Vf + (size_t)b * 128 * 16384 + (size_t)(2 * w) * 1024 + (size_t)l * 8;

  f32x16 acc[2][2] = {};                        // [q32][ct] for c = w*64 + ct*32
  float Lp = 0.f;

  for (int tile = 0; tile < 32; ++tile) {
    const int buf = tile & 1;

    // ---- producer: QK + softmax for keys [tile*128 + kg*32, +32), cols q32p
    {
      const ushort* pk_ = kbase + (size_t)(tile * 4 + kg) * 2048;
      short8 kf0 = *(const short8*)(pk_);
      short8 kf1 = *(const short8*)(pk_ + 512);
      short8 kf2 = *(const short8*)(pk_ + 1024);
      short8 kf3 = *(const short8*)(pk_ + 1536);
      short8 q0 = *(const short8*)(qptr);
      short8 q1 = *(const short8*)(qptr + 16);
      short8 q2 = *(const short8*)(qptr + 32);
      short8 q3 = *(const short8*)(qptr + 48);
      f32x16 s = {};
      __builtin_amdgcn_s_setprio(1);
      s = __builtin_amdgcn_mfma_f32_32x32x16_bf16(kf0, q0, s, 0, 0, 0);
      s = __builtin_amdgcn_mfma_f32_32x32x16_bf16(kf1, q1, s, 0, 0, 0);
      s = __builtin_amdgcn_mfma_f32_32x32x16_bf16(kf2, q2, s, 0, 0, 0);
      s = __builtin_amdgcn_mfma_f32_32x32x16_bf16(kf3, q3, s, 0, 0, 0);
      __builtin_amdgcn_s_setprio(0);

      float sum = 0.f;
#pragma unroll
      for (int r = 0; r < 16; ++r) { s[r] = __builtin_amdgcn_exp2f(s[r]); sum += s[r]; }
      Lp += sum;
      unsigned pk0 = cvt_pk_bf16(s[0],  s[1]),  pk1 = cvt_pk_bf16(s[2],  s[3]);
      unsigned pk2 = cvt_pk_bf16(s[4],  s[5]),  pk3 = cvt_pk_bf16(s[6],  s[7]);
      unsigned pk4 = cvt_pk_bf16(s[8],  s[9]),  pk5 = cvt_pk_bf16(s[10], s[11]);
      unsigned pk6 = cvt_pk_bf16(s[12], s[13]), pk7 = cvt_pk_bf16(s[14], s[15]);
      plane_swap(pk0, pk2); plane_swap(pk1, pk3);
      plane_swap(pk4, pk6); plane_swap(pk5, pk7);
      *(uint2*)&Plds[buf][kg * 2 + 0][q32p][0][l][0] = uint2{pk0, pk1};
      *(uint2*)&Plds[buf][kg * 2 + 0][q32p][1][l][0] = uint2{pk2, pk3};
      *(uint2*)&Plds[buf][kg * 2 + 1][q32p][0][l][0] = uint2{pk4, pk5};
      *(uint2*)&Plds[buf][kg * 2 + 1][q32p][1][l][0] = uint2{pk6, pk7};
    }
    __syncthreads();

    // ---- consumer: PV over all 8 k16-slots, depth-1 V pipeline (transient)
    const ushort* pv0 = vbase + (size_t)(tile * 4) * 16384;
    short8 v0 = *(const short8*)(pv0);
    short8 v1 = *(const short8*)(pv0 + 1024);
#pragma unroll
    for (int k8 = 0; k8 < 8; ++k8) {
      short8 nv0, nv1;
      if (k8 < 7) {
        const ushort* pv = vbase + (size_t)(tile * 4 + ((k8 + 1) >> 1)) * 16384 +
                           (size_t)((k8 + 1) & 1) * 512;
        nv0 = *(const short8*)(pv);
        nv1 = *(const short8*)(pv + 1024);
      }
      uint2 a0 = *(const uint2*)&Plds[buf][k8][0][0][l][0];
      uint2 a1 = *(const uint2*)&Plds[buf][k8][0][1][l][0];
      uint2 b0 = *(const uint2*)&Plds[buf][k8][1][0][l][0];
      uint2 b1 = *(const uint2*)&Plds[buf][k8][1][1][l][0];
      PB B0, B1;
      B0.u[0] = a0.x; B0.u[1] = a0.y; B0.u[2] = a1.x; B0.u[3] = a1.y;
      B1.u[0] = b0.x; B1.u[1] = b0.y; B1.u[2] = b1.x; B1.u[3] = b1.y;
      __builtin_amdgcn_s_setprio(1);
      acc[0][0] = __builtin_amdgcn_mfma_f32_32x32x16_bf16(v0, B0.s8, acc[0][0], 0, 0, 0);
      acc[0][1] = __builtin_amdgcn_mfma_f32_32x32x16_bf16(v1, B0.s8, acc[0][1], 0, 0, 0);
      acc[1][0] = __builtin_amdgcn_mfma_f32_32x32x16_bf16(v0, B1.s8, acc[1][0], 0, 0, 0);
      acc[1][1] = __builtin_amdgcn_mfma_f32_32x32x16_bf16(v1, B1.s8, acc[1][1], 0, 0, 0);
      __builtin_amdgcn_s_setprio(0);
      if (k8 < 7) { v0 = nv0; v1 = nv1; }
    }
    // no trailing barrier: next tile writes the OTHER P buffer (dbuf ledger).
  }

  // ---- L reduction across the 4 key-groups, then epilogue
  Lp += __shfl_xor(Lp, 32);
  Lred[q32p][kg][lq] = Lp;                      // both halves write same value
  __syncthreads();
  float Lt0 = (Lred[0][0][lq] + Lred[0][1][lq]) + (Lred[0][2][lq] + Lred[0][3][lq]);
  float Lt1 = (Lred[1][0][lq] + Lred[1][1][lq]) + (Lred[1][2][lq] + Lred[1][3][lq]);
  const float g = gamma[0];
  const float gi0 = g / Lt0, gi1 = g / Lt1;
#pragma unroll
  for (int ct = 0; ct < 2; ++ct)
#pragma unroll
    for (int r = 0; r < 16; ++r) {
      const int c = w * 64 + ct * 32 + (r & 3) + 8 * (r >> 2) + 4 * h;
      const size_t base = ((size_t)b * CCH + c) * NPIX + qw + lq;
      out[base]      = gi0 * acc[0][ct][r] + x[base];
      out[base + 32] = gi1 * acc[1][ct][r] + x[base + 32];
    }
}

extern "C" void kernel_launch(void* const* d_in, const int* in_sizes, int n_in,
                              void* d_out, int out_size, void* d_ws, size_t ws_size,
                              hipStream_t stream) {
  const float* x     = (const float*)d_in[0];
  const float* wq    = (const float*)d_in[1];
  const float* bq    = (const float*)d_in[2];
  const float* wk    = (const float*)d_in[3];
  const float* bk    = (const float*)d_in[4];
  const float* wv    = (const float*)d_in[5];
  const float* bv    = (const float*)d_in[6];
  const float* gamma = (const float*)d_in[7];
  float* out = (float*)d_out;

  // Xt (32MB bf16) lives in d_out (64MB) — dead before k_attn writes the output.
  ushort* Xt = (ushort*)d_out;
  ushort* Wb = (ushort*)d_ws;                          // 640*512
  ushort* Qb = Wb + (size_t)640 * 512;                 // 8*4096*64 row-major
  ushort* Kf = Qb + (size_t)8 * NPIX * DQK;            // 8*128*4*512  (fragment-order)
  ushort* Vf = Kf + (size_t)8 * 128 * 4 * 512;         // 8*128*16*2*512 (fragment-order)
  // total ws: ~42.8 MB

  k_cast_x<<<dim3(NPIX / 32, CCH / 32, 8), 256, 0, stream>>>(x, Xt);
  k_cast_w<<<(640 * 512 / 4) / 256, 256, 0, stream>>>(wq, wk, wv, Wb);
  k_proj<<<dim3(NPIX / 64, 1, 8), 256, 0, stream>>>(Xt, Wb, bq, bk, bv, Qb, Kf, Vf);
  k_attn<<<dim3(512), 512, 0, stream>>>(Qb, Kf, Vf, x, gamma, out);
}

// Round 18
// 255.635 us; speedup vs baseline: 1.1368x; 1.1093x over previous
//
#include <hip/hip_runtime.h>

typedef float  f32x4  __attribute__((ext_vector_type(4)));
typedef float  f32x16 __attribute__((ext_vector_type(16)));
typedef short  short8 __attribute__((ext_vector_type(8)));
typedef unsigned int uint4v __attribute__((ext_vector_type(4)));

#define LOG2E 1.4426950408889634f
#define NPIX 4096
#define CCH  512
#define DQK  64

__device__ __forceinline__ ushort f2b(float f) {
  union { float f; unsigned u; } v; v.f = f;
  unsigned r = v.u + 0x7fffu + ((v.u >> 16) & 1u);
  return (ushort)(r >> 16);
}

__device__ __forceinline__ unsigned cvt_pk_bf16(float lo, float hi) {
  unsigned r;
  asm("v_cvt_pk_bf16_f32 %0, %1, %2" : "=v"(r) : "v"(lo), "v"(hi));
  return r;
}

// in-place half-swap: a' = {a[0:32), b[0:32)}, b' = {a[32:64), b[32:64)}
__device__ __forceinline__ void plane_swap(unsigned &a, unsigned &b) {
  asm volatile("v_permlane32_swap_b32 %0, %1" : "+v"(a), "+v"(b));
}

// async 16B global -> LDS. NOTE: global src must be PER-LANE; LDS dest is
// wave-uniform base + lane*16 (R17 bug: uniform src replicated one chunk).
__device__ __forceinline__ void gload16(const ushort* g, ushort* l) {
  __builtin_amdgcn_global_load_lds((const __attribute__((address_space(1))) void*)g,
                                   (__attribute__((address_space(3))) void*)l, 16, 0, 0);
}

// x: [B][C][N] f32  ->  Xt: [B][N][C] bf16  (tiled transpose via LDS)
__global__ __launch_bounds__(256) void k_cast_x(const float* __restrict__ x,
                                                ushort* __restrict__ Xt) {
  __shared__ float tile[32][33];
  const int b = blockIdx.z;
  const int n0 = blockIdx.x * 32, c0 = blockIdx.y * 32;
  const int t = threadIdx.x;
  {
    int cc = t >> 3, nn = (t & 7) * 4;
    const float4 v = *(const float4*)&x[((size_t)b * CCH + c0 + cc) * NPIX + n0 + nn];
    tile[cc][nn] = v.x; tile[cc][nn + 1] = v.y; tile[cc][nn + 2] = v.z; tile[cc][nn + 3] = v.w;
  }
  __syncthreads();
  {
    int nr = t >> 3, c4 = (t & 7) * 4;
    ushort4 o;
    o.x = f2b(tile[c4 + 0][nr]); o.y = f2b(tile[c4 + 1][nr]);
    o.z = f2b(tile[c4 + 2][nr]); o.w = f2b(tile[c4 + 3][nr]);
    *(ushort4*)&Xt[((size_t)b * NPIX + n0 + nr) * CCH + c0 + c4] = o;
  }
}

// pack wq(64x512), wk(64x512), wv(512x512) -> Wb[640][512] bf16
__global__ __launch_bounds__(256) void k_cast_w(const float* __restrict__ wq,
                                                const float* __restrict__ wk,
                                                const float* __restrict__ wv,
                                                ushort* __restrict__ Wb) {
  int i = blockIdx.x * 256 + threadIdx.x;
  int idx = i * 4;
  int j = idx >> 9, c = idx & 511;
  const float* src = (j < 64) ? &wq[(size_t)j * 512]
                   : (j < 128) ? &wk[(size_t)(j - 64) * 512]
                               : &wv[(size_t)(j - 128) * 512];
  float4 v = *(const float4*)&src[c];
  ushort4 o; o.x = f2b(v.x); o.y = f2b(v.y); o.z = f2b(v.z); o.w = f2b(v.w);
  *(ushort4*)&Wb[idx] = o;
}

// QKV projection GEMM: out[j,n] = sum_c Wb[j,c]*Xt[n,c] + bias[j]
// Q: fragment-order Qf[b][n32][ks:4][lane:64][e:8] (pre-scaled by LOG2E)
// K: fragment-order Kf[b][n32][ks:4][lane:64][e:8]
// V: fragment-order Vf[b][n32][c32:16][kt:2][lane:64][e:8]
__global__ __launch_bounds__(256) void k_proj(const ushort* __restrict__ Xt,
                                              const ushort* __restrict__ Wb,
                                              const float* __restrict__ bq,
                                              const float* __restrict__ bk,
                                              const float* __restrict__ bv,
                                              ushort* __restrict__ Qf,
                                              ushort* __restrict__ Kf,
                                              ushort* __restrict__ Vf) {
  __shared__ ushort Wl[64][72];
  __shared__ ushort Xl[64][72];
  const int b = blockIdx.z;
  const int n0 = blockIdx.x * 64;
  const int j0 = blockIdx.y * 64;
  const int t = threadIdx.x;
  const int w = t >> 6, l = t & 63;
  const int lr = l & 15, lq = l >> 4;
  const int wj = (w >> 1) * 32, wn = (w & 1) * 32;

  f32x4 acc[2][2];
#pragma unroll
  for (int a = 0; a < 2; ++a)
#pragma unroll
    for (int c = 0; c < 2; ++c) acc[a][c] = f32x4{0.f, 0.f, 0.f, 0.f};

  const int srow = t >> 2, sch = t & 3;
  for (int k0 = 0; k0 < 512; k0 += 64) {
    *(uint4*)&Wl[srow][sch * 8]       = *(const uint4*)&Wb[(size_t)(j0 + srow) * 512 + k0 + sch * 8];
    *(uint4*)&Wl[srow][(sch + 4) * 8] = *(const uint4*)&Wb[(size_t)(j0 + srow) * 512 + k0 + (sch + 4) * 8];
    *(uint4*)&Xl[srow][sch * 8]       = *(const uint4*)&Xt[((size_t)b * NPIX + n0 + srow) * 512 + k0 + sch * 8];
    *(uint4*)&Xl[srow][(sch + 4) * 8] = *(const uint4*)&Xt[((size_t)b * NPIX + n0 + srow) * 512 + k0 + (sch + 4) * 8];
    __syncthreads();
#pragma unroll
    for (int kt = 0; kt < 2; ++kt) {
      short8 af[2], bf[2];
#pragma unroll
      for (int jt = 0; jt < 2; ++jt)
        af[jt] = *(const short8*)&Wl[wj + jt * 16 + lr][kt * 32 + lq * 8];
#pragma unroll
      for (int nt = 0; nt < 2; ++nt)
        bf[nt] = *(const short8*)&Xl[wn + nt * 16 + lr][kt * 32 + lq * 8];
#pragma unroll
      for (int jt = 0; jt < 2; ++jt)
#pragma unroll
        for (int nt = 0; nt < 2; ++nt)
          acc[jt][nt] = __builtin_amdgcn_mfma_f32_16x16x32_bf16(af[jt], bf[nt], acc[jt][nt], 0, 0, 0);
    }
    __syncthreads();
  }

#pragma unroll
  for (int jt = 0; jt < 2; ++jt) {
    const int jb = j0 + wj + jt * 16;
#pragma unroll
    for (int nt = 0; nt < 2; ++nt) {
      const int n = n0 + wn + nt * 16 + lr;
      const int n32 = (n0 + wn) >> 5;
      if (jb < 64) {
        // Q fragment-order (same mapping as K), pre-scaled by LOG2E
        const int kd0 = jb + lq * 4;
        const int ks = jb >> 4;
        const int hl = lq >> 1;
        const int e0 = (lq * 4) & 7;
        const int lp = (nt * 16 + lr) + 32 * hl;
        ushort4 o;
        o.x = f2b(LOG2E * (acc[jt][nt][0] + bq[kd0 + 0]));
        o.y = f2b(LOG2E * (acc[jt][nt][1] + bq[kd0 + 1]));
        o.z = f2b(LOG2E * (acc[jt][nt][2] + bq[kd0 + 2]));
        o.w = f2b(LOG2E * (acc[jt][nt][3] + bq[kd0 + 3]));
        *(ushort4*)&Qf[((size_t)(b * 128 + n32) * 4 + ks) * 512 + lp * 8 + e0] = o;
      } else if (jb < 128) {
        const int kd0 = jb - 64 + lq * 4;
        const int ks = (jb - 64) >> 4;
        const int hl = lq >> 1;
        const int e0 = (lq * 4) & 7;
        const int lp = (nt * 16 + lr) + 32 * hl;
        ushort4 o;
        o.x = f2b(acc[jt][nt][0] + bk[kd0 + 0]);
        o.y = f2b(acc[jt][nt][1] + bk[kd0 + 1]);
        o.z = f2b(acc[jt][nt][2] + bk[kd0 + 2]);
        o.w = f2b(acc[jt][nt][3] + bk[kd0 + 3]);
        *(ushort4*)&Kf[((size_t)(b * 128 + n32) * 4 + ks) * 512 + lp * 8 + e0] = o;
      } else {
        const int kt = nt;
        const int hlv = (lr >> 3) & 1;
        const int e = lr & 7;
#pragma unroll
        for (int r = 0; r < 4; ++r) {
          const int c = jb - 128 + lq * 4 + r;
          Vf[(((size_t)(b * 128 + n32) * 16 + (c >> 5)) * 2 + kt) * 512 +
             (c & 31) * 8 + 256 * hlv + e] = f2b(acc[jt][nt][r] + bv[c]);
        }
      }
    }
  }
}

// flash attention v18: R17 with the per-lane global_load_lds source FIX.
// Block = 512 thr / 8 waves = 64q x 512c. Prologue: Q slice (8KB) staged once.
// Per 128-key tile: stage K(t+1) (16KB, dbuf; per-lane src = chunk cb_+l);
// producer reads kf/qf via conflict-free ds_read_b128 (K dedup 2x, Q off the
// VMEM port); softmax; P B-frags to LDS; barrier (drains stage vmcnt + P lgkm);
// consumer = R14 load-use V + P ds_reads.
// grid = 64qb x 8b = 512 = 2 blocks/CU = 4 waves/SIMD. LDS 73KB.
__global__ __launch_bounds__(512, 4) void k_attn(const ushort* __restrict__ Qf,
                                                 const ushort* __restrict__ Kf,
                                                 const ushort* __restrict__ Vf,
                                                 const float* __restrict__ x,
                                                 const float* __restrict__ gamma,
                                                 float* __restrict__ out) {
  __shared__ unsigned Plds[2][8][2][2][64][2];  // [buf][k16][q32][j2][lane][pair] = 32KB
  __shared__ ushort Klds[2][8192];              // [buf][(g*4+ks)*512 + lane*8] = 32KB
  __shared__ ushort Qlds[4096];                 // [q32*2048 + ks*512 + lane*8] = 8KB
  __shared__ float Lred[2][4][32];              // [q32][kg][q] partial L sums
  const int id = blockIdx.x;
  const int b  = id & 7;                        // XCD via %8 round-robin
  const int qb = id >> 3;                       // 0..63 q-strips of 64
  const int t = threadIdx.x;
  const int w = t >> 6, l = t & 63;
  const int lq = l & 31, h = l >> 5;
  const int kg = w >> 1;                        // producer key-group 0..3
  const int q32p = w & 1;                       // producer q-subtile
  const int qw = qb * 64;

  union PB { uint4v u; short8 s8; };

  const ushort* kslice = Kf + (size_t)(b * 128) * 2048;   // + tile*8192
  const ushort* vbase  = Vf + (size_t)b * 128 * 16384 + (size_t)(2 * w) * 1024 + (size_t)l * 8;

  f32x16 acc[2][2] = {};                        // [q32][ct] for c = w*64 + ct*32
  float Lp = 0.f;

  // stage K tile into kbuf (1024 chunks of 16B; 2 per thread).
  // global src per-lane (chunk cb_+l); LDS dest wave-uniform (lane*16 appended by HW).
  auto stageK = [&](int buf, int tile) {
    const ushort* src = kslice + (size_t)tile * 8192;
#pragma unroll
    for (int i = 0; i < 2; ++i) {
      const int cb_ = i * 512 + w * 64;         // wave-uniform chunk base
      gload16(src + (size_t)(cb_ + l) * 8, &Klds[buf][cb_ * 8]);
    }
  };

  // prologue: stage Q (512 chunks, 1/thread) + K(0)
  gload16(Qf + (size_t)(b * 128 + qb * 2) * 2048 + (size_t)(w * 64 + l) * 8, &Qlds[w * 512]);
  stageK(0, 0);
  __syncthreads();

  for (int tile = 0; tile < 32; ++tile) {
    const int buf = tile & 1;
    if (tile + 1 < 32) stageK(buf ^ 1, tile + 1);

    // ---- producer: QK + softmax for keys [tile*128 + kg*32, +32), cols q32p
    {
      const ushort* kb = &Klds[buf][(kg * 4) * 512 + l * 8];
      short8 kf0 = *(const short8*)(kb);
      short8 kf1 = *(const short8*)(kb + 512);
      short8 kf2 = *(const short8*)(kb + 1024);
      short8 kf3 = *(const short8*)(kb + 1536);
      const ushort* qp = &Qlds[q32p * 2048 + l * 8];
      short8 q0 = *(const short8*)(qp);
      short8 q1 = *(const short8*)(qp + 512);
      short8 q2 = *(const short8*)(qp + 1024);
      short8 q3 = *(const short8*)(qp + 1536);
      f32x16 s = {};
      __builtin_amdgcn_s_setprio(1);
      s = __builtin_amdgcn_mfma_f32_32x32x16_bf16(kf0, q0, s, 0, 0, 0);
      s = __builtin_amdgcn_mfma_f32_32x32x16_bf16(kf1, q1, s, 0, 0, 0);
      s = __builtin_amdgcn_mfma_f32_32x32x16_bf16(kf2, q2, s, 0, 0, 0);
      s = __builtin_amdgcn_mfma_f32_32x32x16_bf16(kf3, q3, s, 0, 0, 0);
      __builtin_amdgcn_s_setprio(0);

      float sum = 0.f;
#pragma unroll
      for (int r = 0; r < 16; ++r) { s[r] = __builtin_amdgcn_exp2f(s[r]); sum += s[r]; }
      Lp += sum;
      unsigned pk0 = cvt_pk_bf16(s[0],  s[1]),  pk1 = cvt_pk_bf16(s[2],  s[3]);
      unsigned pk2 = cvt_pk_bf16(s[4],  s[5]),  pk3 = cvt_pk_bf16(s[6],  s[7]);
      unsigned pk4 = cvt_pk_bf16(s[8],  s[9]),  pk5 = cvt_pk_bf16(s[10], s[11]);
      unsigned pk6 = cvt_pk_bf16(s[12], s[13]), pk7 = cvt_pk_bf16(s[14], s[15]);
      plane_swap(pk0, pk2); plane_swap(pk1, pk3);
      plane_swap(pk4, pk6); plane_swap(pk5, pk7);
      *(uint2*)&Plds[buf][kg * 2 + 0][q32p][0][l][0] = uint2{pk0, pk1};
      *(uint2*)&Plds[buf][kg * 2 + 0][q32p][1][l][0] = uint2{pk2, pk3};
      *(uint2*)&Plds[buf][kg * 2 + 1][q32p][0][l][0] = uint2{pk4, pk5};
      *(uint2*)&Plds[buf][kg * 2 + 1][q32p][1][l][0] = uint2{pk6, pk7};
    }
    __syncthreads();   // drains P-writes (lgkm) + stage(t+1) (vmcnt)

    // ---- consumer: PV over all 8 k16-slots for this wave's 64c slice (R14)
#pragma unroll
    for (int k8 = 0; k8 < 8; ++k8) {
      const ushort* pv = vbase + (size_t)(tile * 4 + (k8 >> 1)) * 16384 + (size_t)(k8 & 1) * 512;
      short8 v0 = *(const short8*)(pv);             // c32 = 2w
      short8 v1 = *(const short8*)(pv + 1024);      // c32 = 2w+1
      uint2 a0 = *(const uint2*)&Plds[buf][k8][0][0][l][0];
      uint2 a1 = *(const uint2*)&Plds[buf][k8][0][1][l][0];
      uint2 b0 = *(const uint2*)&Plds[buf][k8][1][0][l][0];
      uint2 b1 = *(const uint2*)&Plds[buf][k8][1][1][l][0];
      PB B0, B1;
      B0.u[0] = a0.x; B0.u[1] = a0.y; B0.u[2] = a1.x; B0.u[3] = a1.y;
      B1.u[0] = b0.x; B1.u[1] = b0.y; B1.u[2] = b1.x; B1.u[3] = b1.y;
      __builtin_amdgcn_s_setprio(1);
      acc[0][0] = __builtin_amdgcn_mfma_f32_32x32x16_bf16(v0, B0.s8, acc[0][0], 0, 0, 0);
      acc[0][1] = __builtin_amdgcn_mfma_f32_32x32x16_bf16(v1, B0.s8, acc[0][1], 0, 0, 0);
      acc[1][0] = __builtin_amdgcn_mfma_f32_32x32x16_bf16(v0, B1.s8, acc[1][0], 0, 0, 0);
      acc[1][1] = __builtin_amdgcn_mfma_f32_32x32x16_bf16(v1, B1.s8, acc[1][1], 0, 0, 0);
      __builtin_amdgcn_s_setprio(0);
    }
    // no trailing barrier: next tile writes the OTHER P/K buffers (dbuf ledger;
    // stage(t+2) targets kbuf[t&1] only after barrier(t), when produce(t)'s
    // readers are done).
  }

  // ---- L reduction across the 4 key-groups, then epilogue
  Lp += __shfl_xor(Lp, 32);
  Lred[q32p][kg][lq] = Lp;                      // both halves write same value
  __syncthreads();
  float Lt0 = (Lred[0][0][lq] + Lred[0][1][lq]) + (Lred[0][2][lq] + Lred[0][3][lq]);
  float Lt1 = (Lred[1][0][lq] + Lred[1][1][lq]) + (Lred[1][2][lq] + Lred[1][3][lq]);
  const float g = gamma[0];
  const float gi0 = g / Lt0, gi1 = g / Lt1;
#pragma unroll
  for (int ct = 0; ct < 2; ++ct)
#pragma unroll
    for (int r = 0; r < 16; ++r) {
      const int c = w * 64 + ct * 32 + (r & 3) + 8 * (r >> 2) + 4 * h;
      const size_t base = ((size_t)b * CCH + c) * NPIX + qw + lq;
      out[base]      = gi0 * acc[0][ct][r] + x[base];
      out[base + 32] = gi1 * acc[1][ct][r] + x[base + 32];
    }
}

extern "C" void kernel_launch(void* const* d_in, const int* in_sizes, int n_in,
                              void* d_out, int out_size, void* d_ws, size_t ws_size,
                              hipStream_t stream) {
  const float* x     = (const float*)d_in[0];
  const float* wq    = (const float*)d_in[1];
  const float* bq    = (const float*)d_in[2];
  const float* wk    = (const float*)d_in[3];
  const float* bk    = (const float*)d_in[4];
  const float* wv    = (const float*)d_in[5];
  const float* bv    = (const float*)d_in[6];
  const float* gamma = (const float*)d_in[7];
  float* out = (float*)d_out;

  // Xt (32MB bf16) lives in d_out (64MB) — dead before k_attn writes the output.
  ushort* Xt = (ushort*)d_out;
  ushort* Wb = (ushort*)d_ws;                          // 640*512
  ushort* Qf = Wb + (size_t)640 * 512;                 // 8*128*4*512 (fragment-order)
  ushort* Kf = Qf + (size_t)8 * 128 * 4 * 512;         // 8*128*4*512 (fragment-order)
  ushort* Vf = Kf + (size_t)8 * 128 * 4 * 512;         // 8*128*16*2*512 (fragment-order)
  // total ws: ~42.8 MB

  k_cast_x<<<dim3(NPIX / 32, CCH / 32, 8), 256, 0, stream>>>(x, Xt);
  k_cast_w<<<(640 * 512 / 4) / 256, 256, 0, stream>>>(wq, wk, wv, Wb);
  k_proj<<<dim3(NPIX / 64, 640 / 64, 8), 256, 0, stream>>>(Xt, Wb, bq, bk, bv, Qf, Kf, Vf);
  k_attn<<<dim3(512), 512, 0, stream>>>(Qf, Kf, Vf, x, gamma, out);
}

// Round 19
// 241.110 us; speedup vs baseline: 1.2053x; 1.0602x over previous
//
#include <hip/hip_runtime.h>

typedef float  f32x4  __attribute__((ext_vector_type(4)));
typedef float  f32x16 __attribute__((ext_vector_type(16)));
typedef short  short8 __attribute__((ext_vector_type(8)));
typedef unsigned int uint4v __attribute__((ext_vector_type(4)));

#define LOG2E 1.4426950408889634f
#define NPIX 4096
#define CCH  512
#define DQK  64

__device__ __forceinline__ ushort f2b(float f) {
  union { float f; unsigned u; } v; v.f = f;
  unsigned r = v.u + 0x7fffu + ((v.u >> 16) & 1u);
  return (ushort)(r >> 16);
}

__device__ __forceinline__ unsigned cvt_pk_bf16(float lo, float hi) {
  unsigned r;
  asm("v_cvt_pk_bf16_f32 %0, %1, %2" : "=v"(r) : "v"(lo), "v"(hi));
  return r;
}

// in-place half-swap: a' = {a[0:32), b[0:32)}, b' = {a[32:64), b[32:64)}
__device__ __forceinline__ void plane_swap(unsigned &a, unsigned &b) {
  asm volatile("v_permlane32_swap_b32 %0, %1" : "+v"(a), "+v"(b));
}

// async 16B global -> LDS. Global src must be PER-LANE; LDS dest is
// wave-uniform base + lane*16.
__device__ __forceinline__ void gload16(const ushort* g, ushort* l) {
  __builtin_amdgcn_global_load_lds((const __attribute__((address_space(1))) void*)g,
                                   (__attribute__((address_space(3))) void*)l, 16, 0, 0);
}

// x: [B][C][N] f32  ->  Xt: [B][N][C] bf16  (tiled transpose via LDS)
__global__ __launch_bounds__(256) void k_cast_x(const float* __restrict__ x,
                                                ushort* __restrict__ Xt) {
  __shared__ float tile[32][33];
  const int b = blockIdx.z;
  const int n0 = blockIdx.x * 32, c0 = blockIdx.y * 32;
  const int t = threadIdx.x;
  {
    int cc = t >> 3, nn = (t & 7) * 4;
    const float4 v = *(const float4*)&x[((size_t)b * CCH + c0 + cc) * NPIX + n0 + nn];
    tile[cc][nn] = v.x; tile[cc][nn + 1] = v.y; tile[cc][nn + 2] = v.z; tile[cc][nn + 3] = v.w;
  }
  __syncthreads();
  {
    int nr = t >> 3, c4 = (t & 7) * 4;
    ushort4 o;
    o.x = f2b(tile[c4 + 0][nr]); o.y = f2b(tile[c4 + 1][nr]);
    o.z = f2b(tile[c4 + 2][nr]); o.w = f2b(tile[c4 + 3][nr]);
    *(ushort4*)&Xt[((size_t)b * NPIX + n0 + nr) * CCH + c0 + c4] = o;
  }
}

// pack wq(64x512), wk(64x512), wv(512x512) -> Wb[640][512] bf16
__global__ __launch_bounds__(256) void k_cast_w(const float* __restrict__ wq,
                                                const float* __restrict__ wk,
                                                const float* __restrict__ wv,
                                                ushort* __restrict__ Wb) {
  int i = blockIdx.x * 256 + threadIdx.x;
  int idx = i * 4;
  int j = idx >> 9, c = idx & 511;
  const float* src = (j < 64) ? &wq[(size_t)j * 512]
                   : (j < 128) ? &wk[(size_t)(j - 64) * 512]
                               : &wv[(size_t)(j - 128) * 512];
  float4 v = *(const float4*)&src[c];
  ushort4 o; o.x = f2b(v.x); o.y = f2b(v.y); o.z = f2b(v.z); o.w = f2b(v.w);
  *(ushort4*)&Wb[idx] = o;
}

// QKV projection GEMM: out[j,n] = sum_c Wb[j,c]*Xt[n,c] + bias[j]
// Q: fragment-order Qf[b][n32][ks:4][lane:64][e:8] (pre-scaled by LOG2E)
// K: fragment-order Kf[b][n32][ks:4][lane:64][e:8]
// V: fragment-order Vf[b][n32][c32:16][kt:2][lane:64][e:8]
__global__ __launch_bounds__(256) void k_proj(const ushort* __restrict__ Xt,
                                              const ushort* __restrict__ Wb,
                                              const float* __restrict__ bq,
                                              const float* __restrict__ bk,
                                              const float* __restrict__ bv,
                                              ushort* __restrict__ Qf,
                                              ushort* __restrict__ Kf,
                                              ushort* __restrict__ Vf) {
  __shared__ ushort Wl[64][72];
  __shared__ ushort Xl[64][72];
  const int b = blockIdx.z;
  const int n0 = blockIdx.x * 64;
  const int j0 = blockIdx.y * 64;
  const int t = threadIdx.x;
  const int w = t >> 6, l = t & 63;
  const int lr = l & 15, lq = l >> 4;
  const int wj = (w >> 1) * 32, wn = (w & 1) * 32;

  f32x4 acc[2][2];
#pragma unroll
  for (int a = 0; a < 2; ++a)
#pragma unroll
    for (int c = 0; c < 2; ++c) acc[a][c] = f32x4{0.f, 0.f, 0.f, 0.f};

  const int srow = t >> 2, sch = t & 3;
  for (int k0 = 0; k0 < 512; k0 += 64) {
    *(uint4*)&Wl[srow][sch * 8]       = *(const uint4*)&Wb[(size_t)(j0 + srow) * 512 + k0 + sch * 8];
    *(uint4*)&Wl[srow][(sch + 4) * 8] = *(const uint4*)&Wb[(size_t)(j0 + srow) * 512 + k0 + (sch + 4) * 8];
    *(uint4*)&Xl[srow][sch * 8]       = *(const uint4*)&Xt[((size_t)b * NPIX + n0 + srow) * 512 + k0 + sch * 8];
    *(uint4*)&Xl[srow][(sch + 4) * 8] = *(const uint4*)&Xt[((size_t)b * NPIX + n0 + srow) * 512 + k0 + (sch + 4) * 8];
    __syncthreads();
#pragma unroll
    for (int kt = 0; kt < 2; ++kt) {
      short8 af[2], bf[2];
#pragma unroll
      for (int jt = 0; jt < 2; ++jt)
        af[jt] = *(const short8*)&Wl[wj + jt * 16 + lr][kt * 32 + lq * 8];
#pragma unroll
      for (int nt = 0; nt < 2; ++nt)
        bf[nt] = *(const short8*)&Xl[wn + nt * 16 + lr][kt * 32 + lq * 8];
#pragma unroll
      for (int jt = 0; jt < 2; ++jt)
#pragma unroll
        for (int nt = 0; nt < 2; ++nt)
          acc[jt][nt] = __builtin_amdgcn_mfma_f32_16x16x32_bf16(af[jt], bf[nt], acc[jt][nt], 0, 0, 0);
    }
    __syncthreads();
  }

#pragma unroll
  for (int jt = 0; jt < 2; ++jt) {
    const int jb = j0 + wj + jt * 16;
#pragma unroll
    for (int nt = 0; nt < 2; ++nt) {
      const int n = n0 + wn + nt * 16 + lr;
      const int n32 = (n0 + wn) >> 5;
      if (jb < 64) {
        // Q fragment-order (same mapping as K), pre-scaled by LOG2E
        const int kd0 = jb + lq * 4;
        const int ks = jb >> 4;
        const int hl = lq >> 1;
        const int e0 = (lq * 4) & 7;
        const int lp = (nt * 16 + lr) + 32 * hl;
        ushort4 o;
        o.x = f2b(LOG2E * (acc[jt][nt][0] + bq[kd0 + 0]));
        o.y = f2b(LOG2E * (acc[jt][nt][1] + bq[kd0 + 1]));
        o.z = f2b(LOG2E * (acc[jt][nt][2] + bq[kd0 + 2]));
        o.w = f2b(LOG2E * (acc[jt][nt][3] + bq[kd0 + 3]));
        *(ushort4*)&Qf[((size_t)(b * 128 + n32) * 4 + ks) * 512 + lp * 8 + e0] = o;
      } else if (jb < 128) {
        const int kd0 = jb - 64 + lq * 4;
        const int ks = (jb - 64) >> 4;
        const int hl = lq >> 1;
        const int e0 = (lq * 4) & 7;
        const int lp = (nt * 16 + lr) + 32 * hl;
        ushort4 o;
        o.x = f2b(acc[jt][nt][0] + bk[kd0 + 0]);
        o.y = f2b(acc[jt][nt][1] + bk[kd0 + 1]);
        o.z = f2b(acc[jt][nt][2] + bk[kd0 + 2]);
        o.w = f2b(acc[jt][nt][3] + bk[kd0 + 3]);
        *(ushort4*)&Kf[((size_t)(b * 128 + n32) * 4 + ks) * 512 + lp * 8 + e0] = o;
      } else {
        const int kt = nt;
        const int hlv = (lr >> 3) & 1;
        const int e = lr & 7;
#pragma unroll
        for (int r = 0; r < 4; ++r) {
          const int c = jb - 128 + lq * 4 + r;
          Vf[(((size_t)(b * 128 + n32) * 16 + (c >> 5)) * 2 + kt) * 512 +
             (c & 31) * 8 + 256 * hlv + e] = f2b(acc[jt][nt][r] + bv[c]);
        }
      }
    }
  }
}

// flash attention v19: 16-wave block = 128q x 512c (V/K port traffic halved).
// Producer: wave w makes S-subtile (kg=w>>2, q32p=w&3) from LDS-staged K/Q ->
// softmax -> P B-frags to LDS (dbuf). Barrier. Consumer: wave w owns c32=w
// (32 channels) x all 128q: per k16-slot, ONE V fragment load + 4 PV MFMAs
// (acc[4] f32x16 = 64 AGPR — proven envelope). grid = 32qb x 8b = 256 =
// 1 block/CU = 4 waves/SIMD. LDS ~117KB.
__global__ __launch_bounds__(1024, 4) void k_attn(const ushort* __restrict__ Qf,
                                                  const ushort* __restrict__ Kf,
                                                  const ushort* __restrict__ Vf,
                                                  const float* __restrict__ x,
                                                  const float* __restrict__ gamma,
                                                  float* __restrict__ out) {
  __shared__ unsigned Plds[2][8][4][2][64][2];  // [buf][k16][q32][j2][lane][pair] = 64KB
  __shared__ ushort Klds[2][8192];              // [buf][g*2048 + ks*512 + lane*8] = 32KB
  __shared__ ushort Qlds[8192];                 // [q32*2048 + ks*512 + lane*8] = 16KB
  __shared__ float Lred[4][4][32];              // [q32][kg][q] partial L sums
  const int id = blockIdx.x;
  const int b  = id & 7;                        // XCD via %8 round-robin
  const int qb = id >> 3;                       // 0..31 q-strips of 128
  const int t = threadIdx.x;
  const int w = t >> 6, l = t & 63;             // w = 0..15
  const int lq = l & 31, h = l >> 5;
  const int kg = w >> 2;                        // producer key-group 0..3
  const int q32p = w & 3;                       // producer q-subtile 0..3
  const int qw = qb * 128;

  union PB { uint4v u; short8 s8; };

  const ushort* kslice = Kf + (size_t)(b * 128) * 2048;   // + tile*8192
  const ushort* vbase  = Vf + (size_t)b * 128 * 16384 + (size_t)w * 1024 + (size_t)l * 8;

  f32x16 acc[4] = {};                           // [q32] for c32 = w
  float Lp = 0.f;

  // stage K tile (1024 chunks of 16B; 1/thread; per-lane global src)
  auto stageK = [&](int buf, int tile) {
    gload16(kslice + (size_t)tile * 8192 + (size_t)(w * 64 + l) * 8, &Klds[buf][w * 512]);
  };

  // prologue: stage Q (128q = 4 n32 = 16KB; 1024 chunks, 1/thread) + K(0)
  gload16(Qf + (size_t)(b * 128 + qb * 4) * 2048 + (size_t)(w * 64 + l) * 8, &Qlds[w * 512]);
  stageK(0, 0);
  __syncthreads();

  for (int tile = 0; tile < 32; ++tile) {
    const int buf = tile & 1;
    if (tile + 1 < 32) stageK(buf ^ 1, tile + 1);

    // ---- producer: QK + softmax for keys [tile*128 + kg*32, +32), cols q32p
    {
      const ushort* kb = &Klds[buf][kg * 2048 + l * 8];
      short8 kf0 = *(const short8*)(kb);
      short8 kf1 = *(const short8*)(kb + 512);
      short8 kf2 = *(const short8*)(kb + 1024);
      short8 kf3 = *(const short8*)(kb + 1536);
      const ushort* qp = &Qlds[q32p * 2048 + l * 8];
      short8 q0 = *(const short8*)(qp);
      short8 q1 = *(const short8*)(qp + 512);
      short8 q2 = *(const short8*)(qp + 1024);
      short8 q3 = *(const short8*)(qp + 1536);
      f32x16 s = {};
      __builtin_amdgcn_s_setprio(1);
      s = __builtin_amdgcn_mfma_f32_32x32x16_bf16(kf0, q0, s, 0, 0, 0);
      s = __builtin_amdgcn_mfma_f32_32x32x16_bf16(kf1, q1, s, 0, 0, 0);
      s = __builtin_amdgcn_mfma_f32_32x32x16_bf16(kf2, q2, s, 0, 0, 0);
      s = __builtin_amdgcn_mfma_f32_32x32x16_bf16(kf3, q3, s, 0, 0, 0);
      __builtin_amdgcn_s_setprio(0);

      float sum = 0.f;
#pragma unroll
      for (int r = 0; r < 16; ++r) { s[r] = __builtin_amdgcn_exp2f(s[r]); sum += s[r]; }
      Lp += sum;
      unsigned pk0 = cvt_pk_bf16(s[0],  s[1]),  pk1 = cvt_pk_bf16(s[2],  s[3]);
      unsigned pk2 = cvt_pk_bf16(s[4],  s[5]),  pk3 = cvt_pk_bf16(s[6],  s[7]);
      unsigned pk4 = cvt_pk_bf16(s[8],  s[9]),  pk5 = cvt_pk_bf16(s[10], s[11]);
      unsigned pk6 = cvt_pk_bf16(s[12], s[13]), pk7 = cvt_pk_bf16(s[14], s[15]);
      plane_swap(pk0, pk2); plane_swap(pk1, pk3);
      plane_swap(pk4, pk6); plane_swap(pk5, pk7);
      *(uint2*)&Plds[buf][kg * 2 + 0][q32p][0][l][0] = uint2{pk0, pk1};
      *(uint2*)&Plds[buf][kg * 2 + 0][q32p][1][l][0] = uint2{pk2, pk3};
      *(uint2*)&Plds[buf][kg * 2 + 1][q32p][0][l][0] = uint2{pk4, pk5};
      *(uint2*)&Plds[buf][kg * 2 + 1][q32p][1][l][0] = uint2{pk6, pk7};
    }
    __syncthreads();   // drains P-writes (lgkm) + stage(t+1) (vmcnt)

    // ---- consumer: PV over 8 k16-slots for c32 = w, all 4 q32 tiles
#pragma unroll
    for (int k8 = 0; k8 < 8; ++k8) {
      const ushort* pv = vbase + (size_t)(tile * 4 + (k8 >> 1)) * 16384 + (size_t)(k8 & 1) * 512;
      short8 v = *(const short8*)(pv);
      uint2 a0 = *(const uint2*)&Plds[buf][k8][0][0][l][0];
      uint2 a1 = *(const uint2*)&Plds[buf][k8][0][1][l][0];
      uint2 b0 = *(const uint2*)&Plds[buf][k8][1][0][l][0];
      uint2 b1 = *(const uint2*)&Plds[buf][k8][1][1][l][0];
      uint2 c0 = *(const uint2*)&Plds[buf][k8][2][0][l][0];
      uint2 c1 = *(const uint2*)&Plds[buf][k8][2][1][l][0];
      uint2 d0 = *(const uint2*)&Plds[buf][k8][3][0][l][0];
      uint2 d1 = *(const uint2*)&Plds[buf][k8][3][1][l][0];
      PB B0, B1, B2, B3;
      B0.u[0] = a0.x; B0.u[1] = a0.y; B0.u[2] = a1.x; B0.u[3] = a1.y;
      B1.u[0] = b0.x; B1.u[1] = b0.y; B1.u[2] = b1.x; B1.u[3] = b1.y;
      B2.u[0] = c0.x; B2.u[1] = c0.y; B2.u[2] = c1.x; B2.u[3] = c1.y;
      B3.u[0] = d0.x; B3.u[1] = d0.y; B3.u[2] = d1.x; B3.u[3] = d1.y;
      __builtin_amdgcn_s_setprio(1);
      acc[0] = __builtin_amdgcn_mfma_f32_32x32x16_bf16(v, B0.s8, acc[0], 0, 0, 0);
      acc[1] = __builtin_amdgcn_mfma_f32_32x32x16_bf16(v, B1.s8, acc[1], 0, 0, 0);
      acc[2] = __builtin_amdgcn_mfma_f32_32x32x16_bf16(v, B2.s8, acc[2], 0, 0, 0);
      acc[3] = __builtin_amdgcn_mfma_f32_32x32x16_bf16(v, B3.s8, acc[3], 0, 0, 0);
      __builtin_amdgcn_s_setprio(0);
    }
    // no trailing barrier: P dbuf ledger — produce(t+1) writes buf^1 (safe vs
    // consume(t)); produce(t+2) rewrites buf only after barrier(t+1); K stage
    // at top of t+1 rewrites Klds[t&1] only after barrier(t), when all
    // producer(t) ds_reads are done.
  }

  // ---- L reduction across the 4 key-groups, then epilogue
  Lp += __shfl_xor(Lp, 32);
  Lred[q32p][kg][lq] = Lp;                      // both halves write same value
  __syncthreads();
  float Lt[4];
#pragma unroll
  for (int q32 = 0; q32 < 4; ++q32)
    Lt[q32] = (Lred[q32][0][lq] + Lred[q32][1][lq]) + (Lred[q32][2][lq] + Lred[q32][3][lq]);
  const float g = gamma[0];
#pragma unroll
  for (int r = 0; r < 16; ++r) {
    const int c = w * 32 + (r & 3) + 8 * (r >> 2) + 4 * h;
    const size_t base = ((size_t)b * CCH + c) * NPIX + qw + lq;
#pragma unroll
    for (int q32 = 0; q32 < 4; ++q32)
      out[base + q32 * 32] = (g / Lt[q32]) * acc[q32][r] + x[base + q32 * 32];
  }
}

extern "C" void kernel_launch(void* const* d_in, const int* in_sizes, int n_in,
                              void* d_out, int out_size, void* d_ws, size_t ws_size,
                              hipStream_t stream) {
  const float* x     = (const float*)d_in[0];
  const float* wq    = (const float*)d_in[1];
  const float* bq    = (const float*)d_in[2];
  const float* wk    = (const float*)d_in[3];
  const float* bk    = (const float*)d_in[4];
  const float* wv    = (const float*)d_in[5];
  const float* bv    = (const float*)d_in[6];
  const float* gamma = (const float*)d_in[7];
  float* out = (float*)d_out;

  // Xt (32MB bf16) lives in d_out (64MB) — dead before k_attn writes the output.
  ushort* Xt = (ushort*)d_out;
  ushort* Wb = (ushort*)d_ws;                          // 640*512
  ushort* Qf = Wb + (size_t)640 * 512;                 // 8*128*4*512 (fragment-order)
  ushort* Kf = Qf + (size_t)8 * 128 * 4 * 512;         // 8*128*4*512 (fragment-order)
  ushort* Vf = Kf + (size_t)8 * 128 * 4 * 512;         // 8*128*16*2*512 (fragment-order)
  // total ws: ~42.8 MB

  k_cast_x<<<dim3(NPIX / 32, CCH / 32, 8), 256, 0, stream>>>(x, Xt);
  k_cast_w<<<(640 * 512 / 4) / 256, 256, 0, stream>>>(wq, wk, wv, Wb);
  k_proj<<<dim3(NPIX / 64, 640 / 64, 8), 256, 0, stream>>>(Xt, Wb, bq, bk, bv, Qf, Kf, Vf);
  k_attn<<<dim3(256), 1024, 0, stream>>>(Qf, Kf, Vf, x, gamma, out);
}

// Round 20
// 234.046 us; speedup vs baseline: 1.2417x; 1.0302x over previous
//
#include <hip/hip_runtime.h>

typedef float  f32x4  __attribute__((ext_vector_type(4)));
typedef float  f32x16 __attribute__((ext_vector_type(16)));
typedef short  short8 __attribute__((ext_vector_type(8)));
typedef unsigned int uint4v __attribute__((ext_vector_type(4)));

#define LOG2E 1.4426950408889634f
#define NPIX 4096
#define CCH  512
#define DQK  64

__device__ __forceinline__ ushort f2b(float f) {
  union { float f; unsigned u; } v; v.f = f;
  unsigned r = v.u + 0x7fffu + ((v.u >> 16) & 1u);
  return (ushort)(r >> 16);
}

__device__ __forceinline__ unsigned cvt_pk_bf16(float lo, float hi) {
  unsigned r;
  asm("v_cvt_pk_bf16_f32 %0, %1, %2" : "=v"(r) : "v"(lo), "v"(hi));
  return r;
}

// in-place half-swap: a' = {a[0:32), b[0:32)}, b' = {a[32:64), b[32:64)}
__device__ __forceinline__ void plane_swap(unsigned &a, unsigned &b) {
  asm volatile("v_permlane32_swap_b32 %0, %1" : "+v"(a), "+v"(b));
}

// async 16B global -> LDS. Global src must be PER-LANE; LDS dest is
// wave-uniform base + lane*16.
__device__ __forceinline__ void gload16(const ushort* g, ushort* l) {
  __builtin_amdgcn_global_load_lds((const __attribute__((address_space(1))) void*)g,
                                   (__attribute__((address_space(3))) void*)l, 16, 0, 0);
}

// x: [B][C][N] f32  ->  Xt: [B][N][C] bf16  (tiled transpose via LDS)
__global__ __launch_bounds__(256) void k_cast_x(const float* __restrict__ x,
                                                ushort* __restrict__ Xt) {
  __shared__ float tile[32][33];
  const int b = blockIdx.z;
  const int n0 = blockIdx.x * 32, c0 = blockIdx.y * 32;
  const int t = threadIdx.x;
  {
    int cc = t >> 3, nn = (t & 7) * 4;
    const float4 v = *(const float4*)&x[((size_t)b * CCH + c0 + cc) * NPIX + n0 + nn];
    tile[cc][nn] = v.x; tile[cc][nn + 1] = v.y; tile[cc][nn + 2] = v.z; tile[cc][nn + 3] = v.w;
  }
  __syncthreads();
  {
    int nr = t >> 3, c4 = (t & 7) * 4;
    ushort4 o;
    o.x = f2b(tile[c4 + 0][nr]); o.y = f2b(tile[c4 + 1][nr]);
    o.z = f2b(tile[c4 + 2][nr]); o.w = f2b(tile[c4 + 3][nr]);
    *(ushort4*)&Xt[((size_t)b * NPIX + n0 + nr) * CCH + c0 + c4] = o;
  }
}

// pack wq(64x512), wk(64x512), wv(512x512) -> Wb[640][512] bf16
__global__ __launch_bounds__(256) void k_cast_w(const float* __restrict__ wq,
                                                const float* __restrict__ wk,
                                                const float* __restrict__ wv,
                                                ushort* __restrict__ Wb) {
  int i = blockIdx.x * 256 + threadIdx.x;
  int idx = i * 4;
  int j = idx >> 9, c = idx & 511;
  const float* src = (j < 64) ? &wq[(size_t)j * 512]
                   : (j < 128) ? &wk[(size_t)(j - 64) * 512]
                               : &wv[(size_t)(j - 128) * 512];
  float4 v = *(const float4*)&src[c];
  ushort4 o; o.x = f2b(v.x); o.y = f2b(v.y); o.z = f2b(v.z); o.w = f2b(v.w);
  *(ushort4*)&Wb[idx] = o;
}

// QKV projection GEMM: out[j,n] = sum_c Wb[j,c]*Xt[n,c] + bias[j]
// Q: fragment-order Qf[b][n32][ks:4][lane:64][e:8] (pre-scaled by LOG2E)
// K: fragment-order Kf[b][n32][ks:4][lane:64][e:8]
// V: fragment-order Vf[b][n32][c32:16][kt:2][lane:64][e:8]
__global__ __launch_bounds__(256) void k_proj(const ushort* __restrict__ Xt,
                                              const ushort* __restrict__ Wb,
                                              const float* __restrict__ bq,
                                              const float* __restrict__ bk,
                                              const float* __restrict__ bv,
                                              ushort* __restrict__ Qf,
                                              ushort* __restrict__ Kf,
                                              ushort* __restrict__ Vf) {
  __shared__ ushort Wl[64][72];
  __shared__ ushort Xl[64][72];
  const int b = blockIdx.z;
  const int n0 = blockIdx.x * 64;
  const int j0 = blockIdx.y * 64;
  const int t = threadIdx.x;
  const int w = t >> 6, l = t & 63;
  const int lr = l & 15, lq = l >> 4;
  const int wj = (w >> 1) * 32, wn = (w & 1) * 32;

  f32x4 acc[2][2];
#pragma unroll
  for (int a = 0; a < 2; ++a)
#pragma unroll
    for (int c = 0; c < 2; ++c) acc[a][c] = f32x4{0.f, 0.f, 0.f, 0.f};

  const int srow = t >> 2, sch = t & 3;
  for (int k0 = 0; k0 < 512; k0 += 64) {
    *(uint4*)&Wl[srow][sch * 8]       = *(const uint4*)&Wb[(size_t)(j0 + srow) * 512 + k0 + sch * 8];
    *(uint4*)&Wl[srow][(sch + 4) * 8] = *(const uint4*)&Wb[(size_t)(j0 + srow) * 512 + k0 + (sch + 4) * 8];
    *(uint4*)&Xl[srow][sch * 8]       = *(const uint4*)&Xt[((size_t)b * NPIX + n0 + srow) * 512 + k0 + sch * 8];
    *(uint4*)&Xl[srow][(sch + 4) * 8] = *(const uint4*)&Xt[((size_t)b * NPIX + n0 + srow) * 512 + k0 + (sch + 4) * 8];
    __syncthreads();
#pragma unroll
    for (int kt = 0; kt < 2; ++kt) {
      short8 af[2], bf[2];
#pragma unroll
      for (int jt = 0; jt < 2; ++jt)
        af[jt] = *(const short8*)&Wl[wj + jt * 16 + lr][kt * 32 + lq * 8];
#pragma unroll
      for (int nt = 0; nt < 2; ++nt)
        bf[nt] = *(const short8*)&Xl[wn + nt * 16 + lr][kt * 32 + lq * 8];
#pragma unroll
      for (int jt = 0; jt < 2; ++jt)
#pragma unroll
        for (int nt = 0; nt < 2; ++nt)
          acc[jt][nt] = __builtin_amdgcn_mfma_f32_16x16x32_bf16(af[jt], bf[nt], acc[jt][nt], 0, 0, 0);
    }
    __syncthreads();
  }

#pragma unroll
  for (int jt = 0; jt < 2; ++jt) {
    const int jb = j0 + wj + jt * 16;
#pragma unroll
    for (int nt = 0; nt < 2; ++nt) {
      const int n = n0 + wn + nt * 16 + lr;
      const int n32 = (n0 + wn) >> 5;
      if (jb < 64) {
        // Q fragment-order (same mapping as K), pre-scaled by LOG2E
        const int kd0 = jb + lq * 4;
        const int ks = jb >> 4;
        const int hl = lq >> 1;
        const int e0 = (lq * 4) & 7;
        const int lp = (nt * 16 + lr) + 32 * hl;
        ushort4 o;
        o.x = f2b(LOG2E * (acc[jt][nt][0] + bq[kd0 + 0]));
        o.y = f2b(LOG2E * (acc[jt][nt][1] + bq[kd0 + 1]));
        o.z = f2b(LOG2E * (acc[jt][nt][2] + bq[kd0 + 2]));
        o.w = f2b(LOG2E * (acc[jt][nt][3] + bq[kd0 + 3]));
        *(ushort4*)&Qf[((size_t)(b * 128 + n32) * 4 + ks) * 512 + lp * 8 + e0] = o;
      } else if (jb < 128) {
        const int kd0 = jb - 64 + lq * 4;
        const int ks = (jb - 64) >> 4;
        const int hl = lq >> 1;
        const int e0 = (lq * 4) & 7;
        const int lp = (nt * 16 + lr) + 32 * hl;
        ushort4 o;
        o.x = f2b(acc[jt][nt][0] + bk[kd0 + 0]);
        o.y = f2b(acc[jt][nt][1] + bk[kd0 + 1]);
        o.z = f2b(acc[jt][nt][2] + bk[kd0 + 2]);
        o.w = f2b(acc[jt][nt][3] + bk[kd0 + 3]);
        *(ushort4*)&Kf[((size_t)(b * 128 + n32) * 4 + ks) * 512 + lp * 8 + e0] = o;
      } else {
        const int kt = nt;
        const int hlv = (lr >> 3) & 1;
        const int e = lr & 7;
#pragma unroll
        for (int r = 0; r < 4; ++r) {
          const int c = jb - 128 + lq * 4 + r;
          Vf[(((size_t)(b * 128 + n32) * 16 + (c >> 5)) * 2 + kt) * 512 +
             (c & 31) * 8 + 256 * hlv + e] = f2b(acc[jt][nt][r] + bv[c]);
        }
      }
    }
  }
}

// flash attention v20: R19 + contiguous-16B P fragments (b128 LDS ops) +
// batch-issued V loads in consumer.
// 16-wave block = 128q x 512c. Producer: wave w makes S-subtile (kg=w>>2,
// q32p=w&3) from LDS-staged K/Q -> softmax -> P B-frags to LDS as TWO
// ds_write_b128 (dbuf). Barrier. Consumer: wave w owns c32=w x all 128q;
// all 8 V fragment loads issued up-front (8 in flight, transient 32 VGPR);
// per k8: 4x ds_read_b128 P + 4 PV MFMAs. grid = 32qb x 8b = 256 = 1/CU.
__global__ __launch_bounds__(1024, 4) void k_attn(const ushort* __restrict__ Qf,
                                                  const ushort* __restrict__ Kf,
                                                  const ushort* __restrict__ Vf,
                                                  const float* __restrict__ x,
                                                  const float* __restrict__ gamma,
                                                  float* __restrict__ out) {
  __shared__ unsigned Plds[2][8][4][64][4];     // [buf][k16][q32][lane][uint4] = 64KB
  __shared__ ushort Klds[2][8192];              // [buf][g*2048 + ks*512 + lane*8] = 32KB
  __shared__ ushort Qlds[8192];                 // [q32*2048 + ks*512 + lane*8] = 16KB
  __shared__ float Lred[4][4][32];              // [q32][kg][q] partial L sums
  const int id = blockIdx.x;
  const int b  = id & 7;                        // XCD via %8 round-robin
  const int qb = id >> 3;                       // 0..31 q-strips of 128
  const int t = threadIdx.x;
  const int w = t >> 6, l = t & 63;             // w = 0..15
  const int lq = l & 31, h = l >> 5;
  const int kg = w >> 2;                        // producer key-group 0..3
  const int q32p = w & 3;                       // producer q-subtile 0..3
  const int qw = qb * 128;

  union PB { uint4v u; short8 s8; };

  const ushort* kslice = Kf + (size_t)(b * 128) * 2048;   // + tile*8192
  const ushort* vbase  = Vf + (size_t)b * 128 * 16384 + (size_t)w * 1024 + (size_t)l * 8;

  f32x16 acc[4] = {};                           // [q32] for c32 = w
  float Lp = 0.f;

  // stage K tile (1024 chunks of 16B; 1/thread; per-lane global src)
  auto stageK = [&](int buf, int tile) {
    gload16(kslice + (size_t)tile * 8192 + (size_t)(w * 64 + l) * 8, &Klds[buf][w * 512]);
  };

  // prologue: stage Q (128q = 4 n32 = 16KB; 1024 chunks, 1/thread) + K(0)
  gload16(Qf + (size_t)(b * 128 + qb * 4) * 2048 + (size_t)(w * 64 + l) * 8, &Qlds[w * 512]);
  stageK(0, 0);
  __syncthreads();

  for (int tile = 0; tile < 32; ++tile) {
    const int buf = tile & 1;
    if (tile + 1 < 32) stageK(buf ^ 1, tile + 1);

    // ---- producer: QK + softmax for keys [tile*128 + kg*32, +32), cols q32p
    {
      const ushort* kb = &Klds[buf][kg * 2048 + l * 8];
      short8 kf0 = *(const short8*)(kb);
      short8 kf1 = *(const short8*)(kb + 512);
      short8 kf2 = *(const short8*)(kb + 1024);
      short8 kf3 = *(const short8*)(kb + 1536);
      const ushort* qp = &Qlds[q32p * 2048 + l * 8];
      short8 q0 = *(const short8*)(qp);
      short8 q1 = *(const short8*)(qp + 512);
      short8 q2 = *(const short8*)(qp + 1024);
      short8 q3 = *(const short8*)(qp + 1536);
      f32x16 s = {};
      __builtin_amdgcn_s_setprio(1);
      s = __builtin_amdgcn_mfma_f32_32x32x16_bf16(kf0, q0, s, 0, 0, 0);
      s = __builtin_amdgcn_mfma_f32_32x32x16_bf16(kf1, q1, s, 0, 0, 0);
      s = __builtin_amdgcn_mfma_f32_32x32x16_bf16(kf2, q2, s, 0, 0, 0);
      s = __builtin_amdgcn_mfma_f32_32x32x16_bf16(kf3, q3, s, 0, 0, 0);
      __builtin_amdgcn_s_setprio(0);

      float sum = 0.f;
#pragma unroll
      for (int r = 0; r < 16; ++r) { s[r] = __builtin_amdgcn_exp2f(s[r]); sum += s[r]; }
      Lp += sum;
      unsigned pk0 = cvt_pk_bf16(s[0],  s[1]),  pk1 = cvt_pk_bf16(s[2],  s[3]);
      unsigned pk2 = cvt_pk_bf16(s[4],  s[5]),  pk3 = cvt_pk_bf16(s[6],  s[7]);
      unsigned pk4 = cvt_pk_bf16(s[8],  s[9]),  pk5 = cvt_pk_bf16(s[10], s[11]);
      unsigned pk6 = cvt_pk_bf16(s[12], s[13]), pk7 = cvt_pk_bf16(s[14], s[15]);
      plane_swap(pk0, pk2); plane_swap(pk1, pk3);
      plane_swap(pk4, pk6); plane_swap(pk5, pk7);
      *(uint4v*)&Plds[buf][kg * 2 + 0][q32p][l][0] = uint4v{pk0, pk1, pk2, pk3};
      *(uint4v*)&Plds[buf][kg * 2 + 1][q32p][l][0] = uint4v{pk4, pk5, pk6, pk7};
    }
    __syncthreads();   // drains P-writes (lgkm) + stage(t+1) (vmcnt)

    // ---- consumer: batch-issue all 8 V fragment loads, then PV per k16-slot
    short8 vf[8];
#pragma unroll
    for (int k8 = 0; k8 < 8; ++k8)
      vf[k8] = *(const short8*)(vbase + (size_t)(tile * 4 + (k8 >> 1)) * 16384 +
                                (size_t)(k8 & 1) * 512);
#pragma unroll
    for (int k8 = 0; k8 < 8; ++k8) {
      PB B0, B1, B2, B3;
      B0.u = *(const uint4v*)&Plds[buf][k8][0][l][0];
      B1.u = *(const uint4v*)&Plds[buf][k8][1][l][0];
      B2.u = *(const uint4v*)&Plds[buf][k8][2][l][0];
      B3.u = *(const uint4v*)&Plds[buf][k8][3][l][0];
      __builtin_amdgcn_s_setprio(1);
      acc[0] = __builtin_amdgcn_mfma_f32_32x32x16_bf16(vf[k8], B0.s8, acc[0], 0, 0, 0);
      acc[1] = __builtin_amdgcn_mfma_f32_32x32x16_bf16(vf[k8], B1.s8, acc[1], 0, 0, 0);
      acc[2] = __builtin_amdgcn_mfma_f32_32x32x16_bf16(vf[k8], B2.s8, acc[2], 0, 0, 0);
      acc[3] = __builtin_amdgcn_mfma_f32_32x32x16_bf16(vf[k8], B3.s8, acc[3], 0, 0, 0);
      __builtin_amdgcn_s_setprio(0);
    }
    // no trailing barrier: P dbuf ledger — produce(t+1) writes buf^1 (safe vs
    // consume(t)); produce(t+2) rewrites buf only after barrier(t+1); K stage
    // at top of t+1 rewrites Klds[t&1] only after barrier(t).
  }

  // ---- L reduction across the 4 key-groups, then epilogue
  Lp += __shfl_xor(Lp, 32);
  Lred[q32p][kg][lq] = Lp;                      // both halves write same value
  __syncthreads();
  float Lt[4];
#pragma unroll
  for (int q32 = 0; q32 < 4; ++q32)
    Lt[q32] = (Lred[q32][0][lq] + Lred[q32][1][lq]) + (Lred[q32][2][lq] + Lred[q32][3][lq]);
  const float g = gamma[0];
#pragma unroll
  for (int r = 0; r < 16; ++r) {
    const int c = w * 32 + (r & 3) + 8 * (r >> 2) + 4 * h;
    const size_t base = ((size_t)b * CCH + c) * NPIX + qw + lq;
#pragma unroll
    for (int q32 = 0; q32 < 4; ++q32)
      out[base + q32 * 32] = (g / Lt[q32]) * acc[q32][r] + x[base + q32 * 32];
  }
}

extern "C" void kernel_launch(void* const* d_in, const int* in_sizes, int n_in,
                              void* d_out, int out_size, void* d_ws, size_t ws_size,
                              hipStream_t stream) {
  const float* x     = (const float*)d_in[0];
  const float* wq    = (const float*)d_in[1];
  const float* bq    = (const float*)d_in[2];
  const float* wk    = (const float*)d_in[3];
  const float* bk    = (const float*)d_in[4];
  const float* wv    = (const float*)d_in[5];
  const float* bv    = (const float*)d_in[6];
  const float* gamma = (const float*)d_in[7];
  float* out = (float*)d_out;

  // Xt (32MB bf16) lives in d_out (64MB) — dead before k_attn writes the output.
  ushort* Xt = (ushort*)d_out;
  ushort* Wb = (ushort*)d_ws;                          // 640*512
  ushort* Qf = Wb + (size_t)640 * 512;                 // 8*128*4*512 (fragment-order)
  ushort* Kf = Qf + (size_t)8 * 128 * 4 * 512;         // 8*128*4*512 (fragment-order)
  ushort* Vf = Kf + (size_t)8 * 128 * 4 * 512;         // 8*128*16*2*512 (fragment-order)
  // total ws: ~42.8 MB

  k_cast_x<<<dim3(NPIX / 32, CCH / 32, 8), 256, 0, stream>>>(x, Xt);
  k_cast_w<<<(640 * 512 / 4) / 256, 256, 0, stream>>>(wq, wk, wv, Wb);
  k_proj<<<dim3(NPIX / 64, 640 / 64, 8), 256, 0, stream>>>(Xt, Wb, bq, bk, bv, Qf, Kf, Vf);
  k_attn<<<dim3(256), 1024, 0, stream>>>(Qf, Kf, Vf, x, gamma, out);
}